// Round 18
// baseline (216.141 us; speedup 1.0000x reference)
//
#include <hip/hip_runtime.h>

#define N_NODES   1000000
#define N_EDGES   2000000
#define N_FEAT    11
#define HIDDEN    64
#define BATCH     128
#define N_CLASSES 19

#define NPB     2048                      // nodes per bucket (bucket = col>>11)
#define NBUCK   489                       // ceil(1e6/2048)
#define BCAP    5120                      // edges per bucket region
#define EPB     16384                     // edges per partition block (16/thread)
#define PBLK    123                       // ceil(2e6/16384)
#define NSLOT   8                         // pool slots per 256-node chunk
#define NCHUNK  3907                      // ceil(1e6/256)
#define FROW    24                        // fb16 row stride in ushorts (48 B)
#define ZOFF    (256 * FROW)              // zero-row offset (16B-aligned)

typedef __attribute__((ext_vector_type(8))) short v8s;
typedef __attribute__((ext_vector_type(4))) float v4f;

// f32 -> bf16 round-to-nearest-even
__device__ __forceinline__ unsigned f2b(float v) {
    unsigned u = __float_as_uint(v);
    return (u + 0x7FFFu + ((u >> 16) & 1u)) >> 16;
}

// ---- K1: multisplit into fixed-capacity bucket regions (single pass) ----
// 16 edges/thread held in registers across the histogram barrier.
__global__ __launch_bounds__(1024) void part_kernel(const int* __restrict__ row,
                                                    const int* __restrict__ col,
                                                    int* __restrict__ bcnt,
                                                    int* __restrict__ part) {
    __shared__ int lh[512];
    const int t = threadIdx.x;
    if (t < 512) lh[t] = 0;
    __syncthreads();
    const int q0 = (blockIdx.x * EPB) >> 2;
    const int4* col4 = (const int4*)col;
    const int4* row4 = (const int4*)row;
    int4 c[4], r[4];
    bool v[4];
#pragma unroll
    for (int k = 0; k < 4; ++k) {
        int q = q0 + k * 1024 + t;
        v[k] = q < N_EDGES / 4;
        if (v[k]) { c[k] = col4[q]; r[k] = row4[q]; }
    }
#pragma unroll
    for (int k = 0; k < 4; ++k) {
        if (v[k]) {
            atomicAdd(&lh[c[k].x >> 11], 1); atomicAdd(&lh[c[k].y >> 11], 1);
            atomicAdd(&lh[c[k].z >> 11], 1); atomicAdd(&lh[c[k].w >> 11], 1);
        }
    }
    __syncthreads();
    if (t < NBUCK) {
        int n = lh[t];
        if (n) lh[t] = t * BCAP + atomicAdd(&bcnt[t], n);
    }
    __syncthreads();
#pragma unroll
    for (int k = 0; k < 4; ++k) {
        if (v[k]) {
            int p;
            p = atomicAdd(&lh[c[k].x >> 11], 1); part[p] = (r[k].x << 11) | (c[k].x & (NPB - 1));
            p = atomicAdd(&lh[c[k].y >> 11], 1); part[p] = (r[k].y << 11) | (c[k].y & (NPB - 1));
            p = atomicAdd(&lh[c[k].z >> 11], 1); part[p] = (r[k].z << 11) | (c[k].z & (NPB - 1));
            p = atomicAdd(&lh[c[k].w >> 11], 1); part[p] = (r[k].w << 11) | (c[k].w & (NPB - 1));
        }
    }
}

// ---- K2: per-bucket counting sort — shuffle-scan, direct global scatter ----
__global__ __launch_bounds__(1024) void sort2_kernel(const int* __restrict__ part,
                                                     const int* __restrict__ bcnt,
                                                     const float* __restrict__ x,
                                                     int* __restrict__ srcs,
                                                     int* __restrict__ nstart,
                                                     unsigned short* __restrict__ ndeg,
                                                     float* __restrict__ dinv,
                                                     unsigned short* __restrict__ xs) {
    __shared__ int cnt[NPB];       // 8 KB
    __shared__ int off[NPB];       // 8 KB (relative to s0)
    __shared__ int wsum[16];
    __shared__ int stage[BCAP];    // 20 KB — raw bucket edges
    const int t = threadIdx.x, b = blockIdx.x;
    const int lane = t & 63, wv = t >> 6;
    for (int i = t; i < NPB; i += 1024) cnt[i] = 0;
    __syncthreads();
    const int s0 = b * BCAP, m = bcnt[b];
    // fused load + histogram (single global pass over the bucket)
    for (int j = t; j < m; j += 1024) {
        int v = part[s0 + j];
        stage[j] = v;
        atomicAdd(&cnt[v & (NPB - 1)], 1);
    }
    __syncthreads();
    // exclusive scan of 2048 counts: 2/thread, wave-shuffle scan (2 barriers)
    const int i0 = t * 2;
    int c0 = cnt[i0], c1 = cnt[i0 + 1];
    int s = c0 + c1;
    int incl = s;
#pragma unroll
    for (int o = 1; o < 64; o <<= 1) {
        int v = __shfl_up(incl, o, 64);
        if (lane >= o) incl += v;
    }
    if (lane == 63) wsum[wv] = incl;
    __syncthreads();
    if (t < 64) {
        int v = (t < 16) ? wsum[t] : 0;
#pragma unroll
        for (int o = 1; o < 16; o <<= 1) {
            int u = __shfl_up(v, o, 64);
            if (lane >= o) v += u;
        }
        if (t < 16) wsum[t] = v;     // inclusive wave sums
    }
    __syncthreads();
    int woff = (wv == 0) ? 0 : wsum[wv - 1];
    int run = woff + incl - s;       // exclusive prefix for this thread
    off[i0] = run; off[i0 + 1] = run + c0;
    __syncthreads();
    // per-node outputs + fused xpad (bf16, 32B rows), coalesced
    for (int i = t; i < NPB; i += 1024) {
        int n = b * NPB + i;
        if (n < N_NODES) {
            int d = cnt[i];
            float dv = d ? rsqrtf((float)d) : 0.0f;
            dinv[n]   = dv;
            ndeg[n]   = (unsigned short)d;
            nstart[n] = s0 + off[i];
            const float* xr = x + (size_t)n * N_FEAT;
            unsigned h[11];
#pragma unroll
            for (int k = 0; k < 11; ++k) h[k] = f2b(dv * xr[k]);
            uint4 A, B;
            A.x = h[0] | (h[1] << 16); A.y = h[2] | (h[3] << 16);
            A.z = h[4] | (h[5] << 16); A.w = h[6] | (h[7] << 16);
            B.x = h[8] | (h[9] << 16); B.y = h[10]; B.z = 0u; B.w = 0u;
            uint4* o = (uint4*)(xs + (size_t)n * 16);
            o[0] = A; o[1] = B;
        }
    }
    __syncthreads();
    // scatter directly to global (20 KB target region, L2-resident)
    for (int j = t; j < m; j += 1024) {
        int p  = stage[j];
        int cl = p & (NPB - 1);
        int pos = atomicAdd(&off[cl], 1);
        srcs[s0 + pos] = p >> 11;
    }
}

// ---- K3: 4-wide pipelined gather + MFMA + register pooling (unchanged) ----
__global__ __launch_bounds__(256) void gather_pool_kernel(
    const int* __restrict__ srcs, const unsigned short* __restrict__ xs,
    const int* __restrict__ nstart, const unsigned short* __restrict__ ndeg,
    const float* __restrict__ dinv, const int* __restrict__ batch,
    const float* __restrict__ Wc, const float* __restrict__ bc,
    float* __restrict__ pooled, float* __restrict__ countsf) {
    __shared__ unsigned short fb16[ZOFF + 8];   // 256 rows x 48B + zero row
    __shared__ int   sj0[256];
    __shared__ int   sdeg[256];
    __shared__ float sdinv[256];
    __shared__ int   sbid[256];
    __shared__ int   sperm[256];
    __shared__ int   dcnt[32];
    __shared__ int   doff[32];
    __shared__ float pbuf[2 * HIDDEN];
    __shared__ int   pcnt[NSLOT];
    const int t = threadIdx.x, lane = t & 63, w = t >> 6;
    const int quad = lane >> 4;
    const int base = blockIdx.x * 256;
    {
        int n = base + t;
        bool v = n < N_NODES;
        sj0[t]   = v ? nstart[n] : 0;
        sdeg[t]  = v ? (int)ndeg[n] : 0;
        sdinv[t] = v ? dinv[n] : 0.0f;
        sbid[t]  = v ? batch[n] : -1;
    }
    if (t < 2 * HIDDEN) pbuf[t] = 0.0f;
    if (t < NSLOT) pcnt[t] = 0;
    if (t < 32)    dcnt[t] = 0;
    if (t < 4)     ((unsigned*)(fb16 + ZOFF))[t] = 0u;   // zero row for K-pad
    __syncthreads();
    const int bid0 = sbid[0];
    {
        int bid = sbid[t];
        if (bid >= 0) {
            int slot = bid - bid0;
            if (slot >= 0 && slot < NSLOT) atomicAdd(&pcnt[slot], 1);
            else atomicAdd(&countsf[bid], 1.0f);
        }
    }
    // LDS counting sort of 256 nodes by degree -> sperm
    int mybin = sdeg[t] < 31 ? sdeg[t] : 31;
    atomicAdd(&dcnt[mybin], 1);
    __syncthreads();
    if (t < 32) {
        int r = 0;
        for (int i = 0; i < t; ++i) r += dcnt[i];
        doff[t] = r;
    }
    __syncthreads();
    int pos = atomicAdd(&doff[mybin], 1);
    sperm[pos] = t;
    __syncthreads();

    // phase A: 4-wide pipelined gather — 4 independent xs loads in flight
    {
        int i  = sperm[t];
        int j0 = sj0[i], d = sdeg[i];
        const int e = j0 + d;
        float acc[11];
#pragma unroll
        for (int k = 0; k < 11; ++k) acc[k] = 0.0f;
        for (int j = j0; j < e; j += 4) {
            int j1 = (j + 1 < e) ? j + 1 : j;   // clamped: duplicate loads hit L1
            int j2 = (j + 2 < e) ? j + 2 : j;
            int j3 = (j + 3 < e) ? j + 3 : j;
            int r0 = srcs[j], r1 = srcs[j1], r2 = srcs[j2], r3 = srcs[j3];
            const uint4* p0 = (const uint4*)(xs + (size_t)r0 * 16);
            const uint4* p1 = (const uint4*)(xs + (size_t)r1 * 16);
            const uint4* p2 = (const uint4*)(xs + (size_t)r2 * 16);
            const uint4* p3 = (const uint4*)(xs + (size_t)r3 * 16);
            uint4 A0 = p0[0]; uint2 B0 = *(const uint2*)(p0 + 1);
            uint4 A1 = p1[0]; uint2 B1 = *(const uint2*)(p1 + 1);
            uint4 A2 = p2[0]; uint2 B2 = *(const uint2*)(p2 + 1);
            uint4 A3 = p3[0]; uint2 B3 = *(const uint2*)(p3 + 1);
            float m1 = (j + 1 < e) ? 1.0f : 0.0f;
            float m2 = (j + 2 < e) ? 1.0f : 0.0f;
            float m3 = (j + 3 < e) ? 1.0f : 0.0f;
#define ACCF(idx, expr0, expr1, expr2, expr3)                     \
            acc[idx] += __uint_as_float(expr0);                   \
            acc[idx] = fmaf(m1, __uint_as_float(expr1), acc[idx]);\
            acc[idx] = fmaf(m2, __uint_as_float(expr2), acc[idx]);\
            acc[idx] = fmaf(m3, __uint_as_float(expr3), acc[idx]);
            ACCF(0,  A0.x << 16,        A1.x << 16,        A2.x << 16,        A3.x << 16)
            ACCF(1,  A0.x & 0xFFFF0000u, A1.x & 0xFFFF0000u, A2.x & 0xFFFF0000u, A3.x & 0xFFFF0000u)
            ACCF(2,  A0.y << 16,        A1.y << 16,        A2.y << 16,        A3.y << 16)
            ACCF(3,  A0.y & 0xFFFF0000u, A1.y & 0xFFFF0000u, A2.y & 0xFFFF0000u, A3.y & 0xFFFF0000u)
            ACCF(4,  A0.z << 16,        A1.z << 16,        A2.z << 16,        A3.z << 16)
            ACCF(5,  A0.z & 0xFFFF0000u, A1.z & 0xFFFF0000u, A2.z & 0xFFFF0000u, A3.z & 0xFFFF0000u)
            ACCF(6,  A0.w << 16,        A1.w << 16,        A2.w << 16,        A3.w << 16)
            ACCF(7,  A0.w & 0xFFFF0000u, A1.w & 0xFFFF0000u, A2.w & 0xFFFF0000u, A3.w & 0xFFFF0000u)
            ACCF(8,  B0.x << 16,        B1.x << 16,        B2.x << 16,        B3.x << 16)
            ACCF(9,  B0.x & 0xFFFF0000u, B1.x & 0xFFFF0000u, B2.x & 0xFFFF0000u, B3.x & 0xFFFF0000u)
            ACCF(10, B0.y << 16,        B1.y << 16,        B2.y << 16,        B3.y << 16)
#undef ACCF
        }
        unsigned hb[11];
#pragma unroll
        for (int k = 0; k < 11; ++k) hb[k] = f2b(acc[k]);
        uint4 U0, U1;
        U0.x = hb[0] | (hb[1] << 16); U0.y = hb[2]  | (hb[3] << 16);
        U0.z = hb[4] | (hb[5] << 16); U0.w = hb[6]  | (hb[7] << 16);
        U1.x = hb[8] | (hb[9] << 16); U1.y = hb[10]; U1.z = 0u; U1.w = 0u;
        uint4* wp = (uint4*)(fb16 + i * FROW);
        wp[0] = U0; wp[1] = U1;
    }
    __syncthreads();

    // phase B: MFMA  h[256x64] = fb16[256x(11pad32)] @ Wc[(11pad32)x64]
    const int nch = w * 16 + (lane & 15);
    union { v8s v; unsigned short us[8]; } bf;
#pragma unroll
    for (int j = 0; j < 8; ++j) {
        int k = quad * 8 + j;
        bf.us[j] = (k < 11) ? (unsigned short)f2b(Wc[k * HIDDEN + nch]) : (unsigned short)0;
    }
    const float bias_lane = bc[nch];
    float acc0 = 0.0f, acc1 = 0.0f;
#pragma unroll 4
    for (int mtile = 0; mtile < 16; ++mtile) {
        const v8s* ap = (quad < 2)
            ? (const v8s*)(fb16 + (mtile * 16 + (lane & 15)) * FROW + quad * 8)
            : (const v8s*)(fb16 + ZOFF);
        v8s a = *ap;
        v4f d = __builtin_amdgcn_mfma_f32_16x16x32_bf16(a, bf.v, (v4f){0.f, 0.f, 0.f, 0.f}, 0, 0, 0);
#pragma unroll
        for (int r = 0; r < 4; ++r) {
            int node = mtile * 16 + quad * 4 + r;
            int bid  = sbid[node];
            if (bid >= 0) {
                float h = fmaxf(fmaf(sdinv[node], d[r], bias_lane), 0.0f);
                int slot = bid - bid0;
                if (slot == 0)      acc0 += h;
                else if (slot == 1) acc1 += h;
                else atomicAdd(&pooled[(size_t)bid * HIDDEN + nch], h);  // ~never
            }
        }
    }
    atomicAdd(&pbuf[nch], acc0);
    atomicAdd(&pbuf[HIDDEN + nch], acc1);
    __syncthreads();
    for (int s = w; s < 2; s += 4) {
        int c = pcnt[s];
        if (c > 0) {
            atomicAdd(&pooled[(size_t)(bid0 + s) * HIDDEN + lane], pbuf[s * HIDDEN + lane]);
            if (lane == 0) atomicAdd(&countsf[bid0 + s], (float)c);
        }
    }
}

// ---- K4: out = (pooled/cnt) @ W_lin + b_lin ----
__global__ void final_kernel(const float* __restrict__ pooled, const float* __restrict__ counts,
                             const float* __restrict__ Wl, const float* __restrict__ bl,
                             float* __restrict__ out) {
    int i = blockIdx.x * blockDim.x + threadIdx.x;
    if (i >= BATCH * N_CLASSES) return;
    int b = i / N_CLASSES;
    int c = i - b * N_CLASSES;
    float inv = 1.0f / fmaxf(counts[b], 1.0f);
    float s = bl[c];
#pragma unroll 8
    for (int h = 0; h < HIDDEN; ++h)
        s = fmaf(pooled[b * HIDDEN + h] * inv, Wl[h * N_CLASSES + c], s);
    out[i] = s;
}

extern "C" void kernel_launch(void* const* d_in, const int* in_sizes, int n_in,
                              void* d_out, int out_size, void* d_ws, size_t ws_size,
                              hipStream_t stream) {
    // inputs: x, edge_index, y(unused), batch, W_conv, b_conv, W_lin, b_lin
    const float* x     = (const float*)d_in[0];
    const int*   ei    = (const int*)d_in[1];   // [2, E] int32
    const int*   batch = (const int*)d_in[3];
    const float* Wc    = (const float*)d_in[4];
    const float* bc    = (const float*)d_in[5];
    const float* Wl    = (const float*)d_in[6];
    const float* bl    = (const float*)d_in[7];
    float*       out   = (float*)d_out;

    int*            bcnt    = (int*)d_ws;
    float*          pooled  = (float*)(bcnt + 512);
    float*          countsf = pooled + BATCH * HIDDEN;
    unsigned short* xs      = (unsigned short*)(countsf + BATCH);
    int*            nstart  = (int*)(xs + (size_t)N_NODES * 16);
    unsigned short* ndeg    = (unsigned short*)(nstart + N_NODES);
    float*          dinv    = (float*)(ndeg + N_NODES);
    int*            part    = (int*)(dinv + N_NODES);
    int*            srcs    = part + (size_t)NBUCK * BCAP;

    size_t zero_bytes = (512 + BATCH * HIDDEN + BATCH) * 4;
    hipMemsetAsync(d_ws, 0, zero_bytes, stream);

    const int* row = ei;
    const int* col = ei + N_EDGES;

    part_kernel <<<PBLK, 1024, 0, stream>>>(row, col, bcnt, part);
    sort2_kernel<<<NBUCK, 1024, 0, stream>>>(part, bcnt, x, srcs, nstart, ndeg, dinv, xs);
    gather_pool_kernel<<<NCHUNK, 256, 0, stream>>>(srcs, xs, nstart, ndeg, dinv,
                                                   batch, Wc, bc, pooled, countsf);
    final_kernel<<<(BATCH * N_CLASSES + 255) / 256, 256, 0, stream>>>(pooled, countsf, Wl, bl, out);
}

// Round 19
// 210.649 us; speedup vs baseline: 1.0261x; 1.0261x over previous
//
#include <hip/hip_runtime.h>

#define N_NODES   1000000
#define N_EDGES   2000000
#define N_FEAT    11
#define HIDDEN    64
#define BATCH     128
#define N_CLASSES 19

#define NPB     2048                      // nodes per bucket (bucket = col>>11)
#define NBUCK   489                       // ceil(1e6/2048)
#define BCAP    5120                      // edges per bucket region
#define EPB     8192                      // edges per partition block
#define PBLK    245                       // ceil(2e6/8192)
#define NSLOT   8                         // pool slots per 256-node chunk
#define NCHUNK  3907                      // ceil(1e6/256)
#define FROW    24                        // fb16 row stride in ushorts (48 B)
#define ZOFF    (256 * FROW)              // zero-row offset (16B-aligned)

typedef __attribute__((ext_vector_type(8))) short v8s;
typedef __attribute__((ext_vector_type(4))) float v4f;

// f32 -> bf16 round-to-nearest-even
__device__ __forceinline__ unsigned f2b(float v) {
    unsigned u = __float_as_uint(v);
    return (u + 0x7FFFu + ((u >> 16) & 1u)) >> 16;
}

// ---- K1: multisplit into fixed-capacity bucket regions (single pass) ----
__global__ __launch_bounds__(1024) void part_kernel(const int* __restrict__ row,
                                                    const int* __restrict__ col,
                                                    int* __restrict__ bcnt,
                                                    int* __restrict__ part) {
    __shared__ int lh[512];
    const int t = threadIdx.x;
    if (t < 512) lh[t] = 0;
    __syncthreads();
    const int q0 = (blockIdx.x * EPB) >> 2;
    const int4* col4 = (const int4*)col;
    const int4* row4 = (const int4*)row;
    const int qa = q0 + t, qb = q0 + 1024 + t;
    const bool va = qa < N_EDGES / 4, vb = qb < N_EDGES / 4;
    int4 ca, ra, cb, rb;
    if (va) { ca = col4[qa]; ra = row4[qa]; }
    if (vb) { cb = col4[qb]; rb = row4[qb]; }
    if (va) {
        atomicAdd(&lh[ca.x >> 11], 1); atomicAdd(&lh[ca.y >> 11], 1);
        atomicAdd(&lh[ca.z >> 11], 1); atomicAdd(&lh[ca.w >> 11], 1);
    }
    if (vb) {
        atomicAdd(&lh[cb.x >> 11], 1); atomicAdd(&lh[cb.y >> 11], 1);
        atomicAdd(&lh[cb.z >> 11], 1); atomicAdd(&lh[cb.w >> 11], 1);
    }
    __syncthreads();
    if (t < NBUCK) {
        int v = lh[t];
        if (v) lh[t] = t * BCAP + atomicAdd(&bcnt[t], v);
    }
    __syncthreads();
    int p;
    if (va) {
        p = atomicAdd(&lh[ca.x >> 11], 1); part[p] = (ra.x << 11) | (ca.x & (NPB - 1));
        p = atomicAdd(&lh[ca.y >> 11], 1); part[p] = (ra.y << 11) | (ca.y & (NPB - 1));
        p = atomicAdd(&lh[ca.z >> 11], 1); part[p] = (ra.z << 11) | (ca.z & (NPB - 1));
        p = atomicAdd(&lh[ca.w >> 11], 1); part[p] = (ra.w << 11) | (ca.w & (NPB - 1));
    }
    if (vb) {
        p = atomicAdd(&lh[cb.x >> 11], 1); part[p] = (rb.x << 11) | (cb.x & (NPB - 1));
        p = atomicAdd(&lh[cb.y >> 11], 1); part[p] = (rb.y << 11) | (cb.y & (NPB - 1));
        p = atomicAdd(&lh[cb.z >> 11], 1); part[p] = (rb.z << 11) | (cb.z & (NPB - 1));
        p = atomicAdd(&lh[cb.w >> 11], 1); part[p] = (rb.w << 11) | (cb.w & (NPB - 1));
    }
}

// ---- K2: per-bucket counting sort — shuffle-scan, LDS-staged writeout ----
__global__ __launch_bounds__(1024) void sort2_kernel(const int* __restrict__ part,
                                                     const int* __restrict__ bcnt,
                                                     const float* __restrict__ x,
                                                     int* __restrict__ srcs,
                                                     int* __restrict__ nstart,
                                                     unsigned short* __restrict__ ndeg,
                                                     float* __restrict__ dinv,
                                                     unsigned short* __restrict__ xs) {
    __shared__ int cnt[NPB];       // 8 KB
    __shared__ int off[NPB];       // 8 KB
    __shared__ int wsum[16];
    __shared__ int stage[BCAP];    // 20 KB — raw bucket edges
    __shared__ int outb[BCAP];     // 20 KB — sorted srcs
    const int t = threadIdx.x, b = blockIdx.x;
    const int lane = t & 63, wv = t >> 6;
    for (int i = t; i < NPB; i += 1024) cnt[i] = 0;
    __syncthreads();
    const int s0 = b * BCAP, m = bcnt[b];
    // fused load + histogram (single global pass over the bucket)
    for (int j = t; j < m; j += 1024) {
        int v = part[s0 + j];
        stage[j] = v;
        atomicAdd(&cnt[v & (NPB - 1)], 1);
    }
    __syncthreads();
    // exclusive scan of 2048 counts: 2/thread, wave-shuffle scan (2 barriers)
    const int i0 = t * 2;
    int c0 = cnt[i0], c1 = cnt[i0 + 1];
    int s = c0 + c1;
    int incl = s;
#pragma unroll
    for (int o = 1; o < 64; o <<= 1) {
        int v = __shfl_up(incl, o, 64);
        if (lane >= o) incl += v;
    }
    if (lane == 63) wsum[wv] = incl;
    __syncthreads();
    if (t < 64) {
        int v = (t < 16) ? wsum[t] : 0;
#pragma unroll
        for (int o = 1; o < 16; o <<= 1) {
            int u = __shfl_up(v, o, 64);
            if (lane >= o) v += u;
        }
        if (t < 16) wsum[t] = v;     // inclusive wave sums
    }
    __syncthreads();
    int woff = (wv == 0) ? 0 : wsum[wv - 1];
    int run = woff + incl - s;       // exclusive prefix for this thread
    off[i0] = run; off[i0 + 1] = run + c0;
    __syncthreads();
    // per-node outputs + fused xpad (bf16, 32B rows), coalesced
    for (int i = t; i < NPB; i += 1024) {
        int n = b * NPB + i;
        if (n < N_NODES) {
            int d = cnt[i];
            float dv = d ? rsqrtf((float)d) : 0.0f;
            dinv[n]   = dv;
            ndeg[n]   = (unsigned short)d;
            nstart[n] = s0 + off[i];
            const float* xr = x + (size_t)n * N_FEAT;
            unsigned h[11];
#pragma unroll
            for (int k = 0; k < 11; ++k) h[k] = f2b(dv * xr[k]);
            uint4 A, B;
            A.x = h[0] | (h[1] << 16); A.y = h[2] | (h[3] << 16);
            A.z = h[4] | (h[5] << 16); A.w = h[6] | (h[7] << 16);
            B.x = h[8] | (h[9] << 16); B.y = h[10]; B.z = 0u; B.w = 0u;
            uint4* o = (uint4*)(xs + (size_t)n * 16);
            o[0] = A; o[1] = B;
        }
    }
    __syncthreads();
    // LDS->LDS scatter to node-sorted order
    for (int j = t; j < m; j += 1024) {
        int p  = stage[j];
        int cl = p & (NPB - 1);
        int pos = atomicAdd(&off[cl], 1);
        outb[pos] = p >> 11;
    }
    __syncthreads();
    // coalesced int4 writeout
    const int m4 = m >> 2;
    int4* d4 = (int4*)(srcs + s0);
    const int4* s4 = (const int4*)outb;
    for (int j = t; j < m4; j += 1024) d4[j] = s4[j];
    for (int j = (m4 << 2) + t; j < m; j += 1024) srcs[s0 + j] = outb[j];
}

// ---- K3: 4-wide pipelined gather + MFMA + register pooling ----
__global__ __launch_bounds__(256) void gather_pool_kernel(
    const int* __restrict__ srcs, const unsigned short* __restrict__ xs,
    const int* __restrict__ nstart, const unsigned short* __restrict__ ndeg,
    const float* __restrict__ dinv, const int* __restrict__ batch,
    const float* __restrict__ Wc, const float* __restrict__ bc,
    float* __restrict__ pooled, float* __restrict__ countsf) {
    __shared__ unsigned short fb16[ZOFF + 8];   // 256 rows x 48B + zero row
    __shared__ int   sj0[256];
    __shared__ int   sdeg[256];
    __shared__ float sdinv[256];
    __shared__ int   sbid[256];
    __shared__ int   sperm[256];
    __shared__ int   dcnt[32];
    __shared__ int   doff[32];
    __shared__ float pbuf[2 * HIDDEN];
    __shared__ int   pcnt[NSLOT];
    const int t = threadIdx.x, lane = t & 63, w = t >> 6;
    const int quad = lane >> 4;
    const int base = blockIdx.x * 256;
    {
        int n = base + t;
        bool v = n < N_NODES;
        sj0[t]   = v ? nstart[n] : 0;
        sdeg[t]  = v ? (int)ndeg[n] : 0;
        sdinv[t] = v ? dinv[n] : 0.0f;
        sbid[t]  = v ? batch[n] : -1;
    }
    if (t < 2 * HIDDEN) pbuf[t] = 0.0f;
    if (t < NSLOT) pcnt[t] = 0;
    if (t < 32)    dcnt[t] = 0;
    if (t < 4)     ((unsigned*)(fb16 + ZOFF))[t] = 0u;   // zero row for K-pad
    __syncthreads();
    const int bid0 = sbid[0];
    {
        int bid = sbid[t];
        if (bid >= 0) {
            int slot = bid - bid0;
            if (slot >= 0 && slot < NSLOT) atomicAdd(&pcnt[slot], 1);
            else atomicAdd(&countsf[bid], 1.0f);
        }
    }
    // LDS counting sort of 256 nodes by degree -> sperm
    int mybin = sdeg[t] < 31 ? sdeg[t] : 31;
    atomicAdd(&dcnt[mybin], 1);
    __syncthreads();
    if (t < 32) {
        int r = 0;
        for (int i = 0; i < t; ++i) r += dcnt[i];
        doff[t] = r;
    }
    __syncthreads();
    int pos = atomicAdd(&doff[mybin], 1);
    sperm[pos] = t;
    __syncthreads();

    // phase A: 4-wide pipelined gather — 4 independent xs loads in flight
    {
        int i  = sperm[t];
        int j0 = sj0[i], d = sdeg[i];
        const int e = j0 + d;
        float acc[11];
#pragma unroll
        for (int k = 0; k < 11; ++k) acc[k] = 0.0f;
        for (int j = j0; j < e; j += 4) {
            int j1 = (j + 1 < e) ? j + 1 : j;   // clamped: duplicate loads hit L1
            int j2 = (j + 2 < e) ? j + 2 : j;
            int j3 = (j + 3 < e) ? j + 3 : j;
            int r0 = srcs[j], r1 = srcs[j1], r2 = srcs[j2], r3 = srcs[j3];
            const uint4* p0 = (const uint4*)(xs + (size_t)r0 * 16);
            const uint4* p1 = (const uint4*)(xs + (size_t)r1 * 16);
            const uint4* p2 = (const uint4*)(xs + (size_t)r2 * 16);
            const uint4* p3 = (const uint4*)(xs + (size_t)r3 * 16);
            uint4 A0 = p0[0]; uint2 B0 = *(const uint2*)(p0 + 1);
            uint4 A1 = p1[0]; uint2 B1 = *(const uint2*)(p1 + 1);
            uint4 A2 = p2[0]; uint2 B2 = *(const uint2*)(p2 + 1);
            uint4 A3 = p3[0]; uint2 B3 = *(const uint2*)(p3 + 1);
            float m1 = (j + 1 < e) ? 1.0f : 0.0f;
            float m2 = (j + 2 < e) ? 1.0f : 0.0f;
            float m3 = (j + 3 < e) ? 1.0f : 0.0f;
#define ACCF(idx, expr0, expr1, expr2, expr3)                     \
            acc[idx] += __uint_as_float(expr0);                   \
            acc[idx] = fmaf(m1, __uint_as_float(expr1), acc[idx]);\
            acc[idx] = fmaf(m2, __uint_as_float(expr2), acc[idx]);\
            acc[idx] = fmaf(m3, __uint_as_float(expr3), acc[idx]);
            ACCF(0,  A0.x << 16,        A1.x << 16,        A2.x << 16,        A3.x << 16)
            ACCF(1,  A0.x & 0xFFFF0000u, A1.x & 0xFFFF0000u, A2.x & 0xFFFF0000u, A3.x & 0xFFFF0000u)
            ACCF(2,  A0.y << 16,        A1.y << 16,        A2.y << 16,        A3.y << 16)
            ACCF(3,  A0.y & 0xFFFF0000u, A1.y & 0xFFFF0000u, A2.y & 0xFFFF0000u, A3.y & 0xFFFF0000u)
            ACCF(4,  A0.z << 16,        A1.z << 16,        A2.z << 16,        A3.z << 16)
            ACCF(5,  A0.z & 0xFFFF0000u, A1.z & 0xFFFF0000u, A2.z & 0xFFFF0000u, A3.z & 0xFFFF0000u)
            ACCF(6,  A0.w << 16,        A1.w << 16,        A2.w << 16,        A3.w << 16)
            ACCF(7,  A0.w & 0xFFFF0000u, A1.w & 0xFFFF0000u, A2.w & 0xFFFF0000u, A3.w & 0xFFFF0000u)
            ACCF(8,  B0.x << 16,        B1.x << 16,        B2.x << 16,        B3.x << 16)
            ACCF(9,  B0.x & 0xFFFF0000u, B1.x & 0xFFFF0000u, B2.x & 0xFFFF0000u, B3.x & 0xFFFF0000u)
            ACCF(10, B0.y << 16,        B1.y << 16,        B2.y << 16,        B3.y << 16)
#undef ACCF
        }
        unsigned hb[11];
#pragma unroll
        for (int k = 0; k < 11; ++k) hb[k] = f2b(acc[k]);
        uint4 U0, U1;
        U0.x = hb[0] | (hb[1] << 16); U0.y = hb[2]  | (hb[3] << 16);
        U0.z = hb[4] | (hb[5] << 16); U0.w = hb[6]  | (hb[7] << 16);
        U1.x = hb[8] | (hb[9] << 16); U1.y = hb[10]; U1.z = 0u; U1.w = 0u;
        uint4* wp = (uint4*)(fb16 + i * FROW);
        wp[0] = U0; wp[1] = U1;
    }
    __syncthreads();

    // phase B: MFMA  h[256x64] = fb16[256x(11pad32)] @ Wc[(11pad32)x64]
    const int nch = w * 16 + (lane & 15);
    union { v8s v; unsigned short us[8]; } bf;
#pragma unroll
    for (int j = 0; j < 8; ++j) {
        int k = quad * 8 + j;
        bf.us[j] = (k < 11) ? (unsigned short)f2b(Wc[k * HIDDEN + nch]) : (unsigned short)0;
    }
    const float bias_lane = bc[nch];
    float acc0 = 0.0f, acc1 = 0.0f;
#pragma unroll 4
    for (int mtile = 0; mtile < 16; ++mtile) {
        const v8s* ap = (quad < 2)
            ? (const v8s*)(fb16 + (mtile * 16 + (lane & 15)) * FROW + quad * 8)
            : (const v8s*)(fb16 + ZOFF);
        v8s a = *ap;
        v4f d = __builtin_amdgcn_mfma_f32_16x16x32_bf16(a, bf.v, (v4f){0.f, 0.f, 0.f, 0.f}, 0, 0, 0);
#pragma unroll
        for (int r = 0; r < 4; ++r) {
            int node = mtile * 16 + quad * 4 + r;
            int bid  = sbid[node];
            if (bid >= 0) {
                float h = fmaxf(fmaf(sdinv[node], d[r], bias_lane), 0.0f);
                int slot = bid - bid0;
                if (slot == 0)      acc0 += h;
                else if (slot == 1) acc1 += h;
                else atomicAdd(&pooled[(size_t)bid * HIDDEN + nch], h);  // ~never
            }
        }
    }
    atomicAdd(&pbuf[nch], acc0);
    atomicAdd(&pbuf[HIDDEN + nch], acc1);
    __syncthreads();
    for (int s = w; s < 2; s += 4) {
        int c = pcnt[s];
        if (c > 0) {
            atomicAdd(&pooled[(size_t)(bid0 + s) * HIDDEN + lane], pbuf[s * HIDDEN + lane]);
            if (lane == 0) atomicAdd(&countsf[bid0 + s], (float)c);
        }
    }
}

// ---- K4: out = (pooled/cnt) @ W_lin + b_lin ----
__global__ void final_kernel(const float* __restrict__ pooled, const float* __restrict__ counts,
                             const float* __restrict__ Wl, const float* __restrict__ bl,
                             float* __restrict__ out) {
    int i = blockIdx.x * blockDim.x + threadIdx.x;
    if (i >= BATCH * N_CLASSES) return;
    int b = i / N_CLASSES;
    int c = i - b * N_CLASSES;
    float inv = 1.0f / fmaxf(counts[b], 1.0f);
    float s = bl[c];
#pragma unroll 8
    for (int h = 0; h < HIDDEN; ++h)
        s = fmaf(pooled[b * HIDDEN + h] * inv, Wl[h * N_CLASSES + c], s);
    out[i] = s;
}

extern "C" void kernel_launch(void* const* d_in, const int* in_sizes, int n_in,
                              void* d_out, int out_size, void* d_ws, size_t ws_size,
                              hipStream_t stream) {
    // inputs: x, edge_index, y(unused), batch, W_conv, b_conv, W_lin, b_lin
    const float* x     = (const float*)d_in[0];
    const int*   ei    = (const int*)d_in[1];   // [2, E] int32
    const int*   batch = (const int*)d_in[3];
    const float* Wc    = (const float*)d_in[4];
    const float* bc    = (const float*)d_in[5];
    const float* Wl    = (const float*)d_in[6];
    const float* bl    = (const float*)d_in[7];
    float*       out   = (float*)d_out;

    int*            bcnt    = (int*)d_ws;
    float*          pooled  = (float*)(bcnt + 512);
    float*          countsf = pooled + BATCH * HIDDEN;
    unsigned short* xs      = (unsigned short*)(countsf + BATCH);
    int*            nstart  = (int*)(xs + (size_t)N_NODES * 16);
    unsigned short* ndeg    = (unsigned short*)(nstart + N_NODES);
    float*          dinv    = (float*)(ndeg + N_NODES);
    int*            part    = (int*)(dinv + N_NODES);
    int*            srcs    = part + (size_t)NBUCK * BCAP;

    size_t zero_bytes = (512 + BATCH * HIDDEN + BATCH) * 4;
    hipMemsetAsync(d_ws, 0, zero_bytes, stream);

    const int* row = ei;
    const int* col = ei + N_EDGES;

    part_kernel <<<PBLK, 1024, 0, stream>>>(row, col, bcnt, part);
    sort2_kernel<<<NBUCK, 1024, 0, stream>>>(part, bcnt, x, srcs, nstart, ndeg, dinv, xs);
    gather_pool_kernel<<<NCHUNK, 256, 0, stream>>>(srcs, xs, nstart, ndeg, dinv,
                                                   batch, Wc, bc, pooled, countsf);
    final_kernel<<<(BATCH * N_CLASSES + 255) / 256, 256, 0, stream>>>(pooled, countsf, Wl, bl, out);
}